// Round 1
// baseline (353.913 us; speedup 1.0000x reference)
//
#include <hip/hip_runtime.h>

typedef __attribute__((ext_vector_type(8))) short vbf8;
typedef __attribute__((ext_vector_type(4))) short vbf4;
typedef __attribute__((ext_vector_type(4))) float vf4;

__device__ __forceinline__ short f2bf(float f) {
  union { float f; unsigned int u; } v; v.f = f;
  unsigned int r = v.u + 0x7fffu + ((v.u >> 16) & 1u);
  return (short)(r >> 16);
}

__device__ __forceinline__ void gload16(const void* g, void* l) {
  __builtin_amdgcn_global_load_lds(
      (const __attribute__((address_space(1))) unsigned int*)g,
      (__attribute__((address_space(3))) unsigned int*)l, 16, 0, 0);
}

// ---------- f32 -> bf16 convert, 4 elems/thread, exact grids ----------
__global__ __launch_bounds__(256) void cvt_kernel(const float* __restrict__ src,
                                                  short* __restrict__ dst, int n) {
  int i = (blockIdx.x * 256 + threadIdx.x) * 4;
  if (i >= n) return;
  float4 v = *(const float4*)(src + i);
  vbf4 o;
  o.x = f2bf(v.x); o.y = f2bf(v.y); o.z = f2bf(v.z); o.w = f2bf(v.w);
  *(vbf4*)(dst + i) = o;
}

// ---------- GEMM C = A * B^T  (A [M][K], B [N][K], both bf16, K-contiguous) ----------
// EPI 0: QKV projection epilogue (scatter to Q/K/Vt head layouts, Q pre-scaled 0.125)
// EPI 1: output projection epilogue (add bias, f32 out [M][1024])
template <int EPI>
__global__ __launch_bounds__(256) void gemm_bt(
    const short* __restrict__ A, const short* __restrict__ Bw, int K,
    short* __restrict__ qb, short* __restrict__ kb, short* __restrict__ vtb,
    const float* __restrict__ bo, float* __restrict__ outp) {
  __shared__ __align__(16) short As[128 * 32];
  __shared__ __align__(16) short Bs[128 * 32];
  const int lane = threadIdx.x & 63;
  const int w = threadIdx.x >> 6;
  const int wr = w >> 1, wc = w & 1;
  const int m0 = blockIdx.y * 128, n0 = blockIdx.x * 128;

  // staging: wave w owns 32 rows of A-tile and B-tile; 2 x 1KB global_load_lds each
  const short* ga = A + (size_t)(m0 + w * 32 + (lane >> 2)) * K + (lane & 3) * 8;
  const short* gb = Bw + (size_t)(n0 + w * 32 + (lane >> 2)) * K + (lane & 3) * 8;
  short* lA = As + w * 1024;
  short* lB = Bs + w * 1024;

  vf4 acc[4][4];
#pragma unroll
  for (int i = 0; i < 4; ++i)
#pragma unroll
    for (int j = 0; j < 4; ++j) acc[i][j] = (vf4){0.f, 0.f, 0.f, 0.f};

  const int ar = wr * 64 + (lane & 15);
  const int br = wc * 64 + (lane & 15);
  const int kk = (lane >> 4) * 8;

  for (int k0 = 0; k0 < K; k0 += 32) {
    gload16(ga + k0, lA);
    gload16(ga + k0 + 16 * K, lA + 512);
    gload16(gb + k0, lB);
    gload16(gb + k0 + 16 * K, lB + 512);
    __syncthreads();
    vbf8 af[4], bfr[4];
#pragma unroll
    for (int mf = 0; mf < 4; ++mf) af[mf] = *(const vbf8*)(As + (ar + mf * 16) * 32 + kk);
#pragma unroll
    for (int nf = 0; nf < 4; ++nf) bfr[nf] = *(const vbf8*)(Bs + (br + nf * 16) * 32 + kk);
#pragma unroll
    for (int mf = 0; mf < 4; ++mf)
#pragma unroll
      for (int nf = 0; nf < 4; ++nf)
        acc[mf][nf] = __builtin_amdgcn_mfma_f32_16x16x32_bf16(af[mf], bfr[nf], acc[mf][nf], 0, 0, 0);
    __syncthreads();
  }

#pragma unroll
  for (int mf = 0; mf < 4; ++mf) {
    const int mbase = m0 + wr * 64 + mf * 16 + (lane >> 4) * 4;
#pragma unroll
    for (int nf = 0; nf < 4; ++nf) {
      vf4 v = acc[mf][nf];
      const int n = n0 + wc * 64 + nf * 16 + (lane & 15);
      if (EPI == 0) {
        const int region = n >> 10;  // 0=Q 1=K 2=V
        const int nn = n & 1023;
        const int h = nn >> 6, d = nn & 63;
        if (region == 0) {
#pragma unroll
          for (int i = 0; i < 4; ++i) {
            const int m = mbase + i;
            const int b = m >> 11, t = m & 2047;
            qb[((size_t)(b * 16 + h) * 2048 + t) * 64 + d] = f2bf(v[i] * 0.125f);
          }
        } else if (region == 1) {
#pragma unroll
          for (int i = 0; i < 4; ++i) {
            const int m = mbase + i;
            const int b = m >> 11, t = m & 2047;
            kb[((size_t)(b * 16 + h) * 2048 + t) * 64 + d] = f2bf(v[i]);
          }
        } else {
          const int b = mbase >> 11, t = mbase & 2047;
          vbf4 o;
          o.x = f2bf(v.x); o.y = f2bf(v.y); o.z = f2bf(v.z); o.w = f2bf(v.w);
          *(vbf4*)(vtb + ((size_t)(b * 16 + h) * 64 + d) * 2048 + t) = o;
        }
      } else {
        const float bias = bo[n];
#pragma unroll
        for (int i = 0; i < 4; ++i) {
          const int m = mbase + i;
          outp[(size_t)m * 1024 + n] = v[i] + bias;
        }
      }
    }
  }
}

// ---------- flash attention, causal ----------
// grid (T/128, H, B), 256 threads = 4 waves, each wave owns 32 q-rows.
// Q pre-scaled by 1/sqrt(64). Q/K layout [B,H,T,64]; V transposed [B,H,64,T].
__global__ __launch_bounds__(256) void attn_kernel(
    const short* __restrict__ Qh, const short* __restrict__ Kh,
    const short* __restrict__ Vt, short* __restrict__ ctx) {
  __shared__ __align__(16) short Ks[64 * 72];
  __shared__ __align__(16) short Vs[64 * 72];
  __shared__ __align__(16) short Ps[4][32 * 72];

  const int lane = threadIdx.x & 63;
  const int w = threadIdx.x >> 6;
  const int qt = blockIdx.x, h = blockIdx.y, b = blockIdx.z;
  const size_t bh = (size_t)(b * 16 + h) * 131072;
  const short* Qp = Qh + bh;
  const short* Kp = Kh + bh;
  const short* Vp = Vt + bh;
  const int q0 = qt * 128;
  const int wq0 = q0 + w * 32;

  // Q fragments live in registers for the whole kv loop
  vbf8 qfr[2][2];
#pragma unroll
  for (int qfi = 0; qfi < 2; ++qfi)
#pragma unroll
    for (int ks = 0; ks < 2; ++ks)
      qfr[qfi][ks] = *(const vbf8*)(Qp + (size_t)(wq0 + qfi * 16 + (lane & 15)) * 64 +
                                    ks * 32 + (lane >> 4) * 8);

  vf4 o[2][4];
  float mrow[2][4], lrow[2][4];
#pragma unroll
  for (int qfi = 0; qfi < 2; ++qfi) {
#pragma unroll
    for (int df = 0; df < 4; ++df) o[qfi][df] = (vf4){0.f, 0.f, 0.f, 0.f};
#pragma unroll
    for (int i = 0; i < 4; ++i) { mrow[qfi][i] = -1e30f; lrow[qfi][i] = 0.f; }
  }

  const int nt = q0 / 64 + 2;
  for (int t = 0; t < nt; ++t) {
    const int k0 = t * 64;
    // stage K tile [64 kv][64 d] and Vt tile [64 d][64 kv], padded stride 72
#pragma unroll
    for (int it = 0; it < 2; ++it) {
      const int c = threadIdx.x + it * 256;
      const int r = c >> 3, c8 = (c & 7) * 8;
      *(vbf8*)(Ks + r * 72 + c8) = *(const vbf8*)(Kp + (size_t)(k0 + r) * 64 + c8);
      *(vbf8*)(Vs + r * 72 + c8) = *(const vbf8*)(Vp + (size_t)r * 2048 + k0 + c8);
    }
    __syncthreads();

    if (k0 < wq0 + 32) {                       // tile not fully masked for this wave
      const bool needmask = (k0 + 64 > wq0);
#pragma unroll
      for (int qfi = 0; qfi < 2; ++qfi) {
        // S = Q K^T  (already scaled via Q)
        vf4 s[4];
#pragma unroll
        for (int kf = 0; kf < 4; ++kf) {
          s[kf] = (vf4){0.f, 0.f, 0.f, 0.f};
#pragma unroll
          for (int ks = 0; ks < 2; ++ks) {
            const vbf8 kfrag = *(const vbf8*)(Ks + (kf * 16 + (lane & 15)) * 72 +
                                              ks * 32 + (lane >> 4) * 8);
            s[kf] = __builtin_amdgcn_mfma_f32_16x16x32_bf16(qfr[qfi][ks], kfrag, s[kf], 0, 0, 0);
          }
        }
        if (needmask) {
          const int qr = wq0 + qfi * 16 + (lane >> 4) * 4;
#pragma unroll
          for (int kf = 0; kf < 4; ++kf) {
            const int kc = k0 + kf * 16 + (lane & 15);
#pragma unroll
            for (int i = 0; i < 4; ++i)
              if (kc > qr + i) s[kf][i] = -1e30f;
          }
        }
        // online softmax (rows live across 16-lane groups)
        float tmax[4], al[4], rs[4];
#pragma unroll
        for (int i = 0; i < 4; ++i) {
          float mx = fmaxf(fmaxf(s[0][i], s[1][i]), fmaxf(s[2][i], s[3][i]));
          mx = fmaxf(mx, __shfl_xor(mx, 1));
          mx = fmaxf(mx, __shfl_xor(mx, 2));
          mx = fmaxf(mx, __shfl_xor(mx, 4));
          mx = fmaxf(mx, __shfl_xor(mx, 8));
          tmax[i] = mx;
        }
#pragma unroll
        for (int i = 0; i < 4; ++i) {
          const float mn = fmaxf(mrow[qfi][i], tmax[i]);
          al[i] = __expf(mrow[qfi][i] - mn);
          mrow[qfi][i] = mn;
          rs[i] = 0.f;
        }
#pragma unroll
        for (int kf = 0; kf < 4; ++kf)
#pragma unroll
          for (int i = 0; i < 4; ++i) {
            const float p = __expf(s[kf][i] - mrow[qfi][i]);
            s[kf][i] = p;
            rs[i] += p;
          }
#pragma unroll
        for (int i = 0; i < 4; ++i) {
          rs[i] += __shfl_xor(rs[i], 1);
          rs[i] += __shfl_xor(rs[i], 2);
          rs[i] += __shfl_xor(rs[i], 4);
          rs[i] += __shfl_xor(rs[i], 8);
          lrow[qfi][i] = lrow[qfi][i] * al[i] + rs[i];
        }
#pragma unroll
        for (int df = 0; df < 4; ++df)
#pragma unroll
          for (int i = 0; i < 4; ++i) o[qfi][df][i] *= al[i];

        // P -> LDS (D-layout -> A-layout transpose round-trip, wave-private)
        const int prow = (lane >> 4) * 4;
#pragma unroll
        for (int kf = 0; kf < 4; ++kf)
#pragma unroll
          for (int i = 0; i < 4; ++i)
            Ps[w][(qfi * 16 + prow + i) * 72 + kf * 16 + (lane & 15)] = f2bf(s[kf][i]);

        // ctx += P @ V   (B operand from Vt: k-contiguous)
#pragma unroll
        for (int ks2 = 0; ks2 < 2; ++ks2) {
          const vbf8 pa = *(const vbf8*)(&Ps[w][(qfi * 16 + (lane & 15)) * 72 +
                                               ks2 * 32 + (lane >> 4) * 8]);
#pragma unroll
          for (int df = 0; df < 4; ++df) {
            const vbf8 vb = *(const vbf8*)(Vs + (df * 16 + (lane & 15)) * 72 +
                                           ks2 * 32 + (lane >> 4) * 8);
            o[qfi][df] = __builtin_amdgcn_mfma_f32_16x16x32_bf16(pa, vb, o[qfi][df], 0, 0, 0);
          }
        }
      }
    }
    __syncthreads();
  }

  // normalize + write ctx [B*T][1024] bf16
#pragma unroll
  for (int qfi = 0; qfi < 2; ++qfi) {
#pragma unroll
    for (int i = 0; i < 4; ++i) {
      const float inv = 1.f / lrow[qfi][i];
      const int q = wq0 + qfi * 16 + (lane >> 4) * 4 + i;
      short* dst = ctx + (size_t)(b * 2048 + q) * 1024 + h * 64;
#pragma unroll
      for (int df = 0; df < 4; ++df)
        dst[df * 16 + (lane & 15)] = f2bf(o[qfi][df][i] * inv);
    }
  }
}

extern "C" void kernel_launch(void* const* d_in, const int* in_sizes, int n_in,
                              void* d_out, int out_size, void* d_ws, size_t ws_size,
                              hipStream_t stream) {
  const float* x  = (const float*)d_in[0];
  const float* Wq = (const float*)d_in[1];
  const float* Wk = (const float*)d_in[2];
  const float* Wv = (const float*)d_in[3];
  const float* Wo = (const float*)d_in[4];
  const float* bo = (const float*)d_in[5];
  float* out = (float*)d_out;

  char* ws = (char*)d_ws;
  short* xb   = (short*)(ws);                  // 16 MB (x bf16), reused as ctx later
  short* wqkv = (short*)(ws + 16777216);       // 6 MB, reused as Wo bf16 later
  short* qb   = (short*)(ws + 23068672);       // 16 MB
  short* kb   = (short*)(ws + 39845888);       // 16 MB
  short* vtb  = (short*)(ws + 56623104);       // 16 MB  (V transposed [B,H,64,T])
  short* ctxb = xb;
  short* wob  = wqkv;

  cvt_kernel<<<8192, 256, 0, stream>>>(x, xb, 8388608);
  cvt_kernel<<<1024, 256, 0, stream>>>(Wq, wqkv, 1048576);
  cvt_kernel<<<1024, 256, 0, stream>>>(Wk, wqkv + 1048576, 1048576);
  cvt_kernel<<<1024, 256, 0, stream>>>(Wv, wqkv + 2097152, 1048576);
  gemm_bt<0><<<dim3(24, 64), 256, 0, stream>>>(xb, wqkv, 1024, qb, kb, vtb, nullptr, nullptr);
  cvt_kernel<<<1024, 256, 0, stream>>>(Wo, wob, 1048576);
  attn_kernel<<<dim3(16, 16, 4), 256, 0, stream>>>(qb, kb, vtb, ctxb);
  gemm_bt<1><<<dim3(8, 64), 256, 0, stream>>>(ctxb, wob, 1024, nullptr, nullptr, nullptr, bo, out);
}

// Round 2
// 337.245 us; speedup vs baseline: 1.0494x; 1.0494x over previous
//
#include <hip/hip_runtime.h>

typedef __attribute__((ext_vector_type(8))) short vbf8;
typedef __attribute__((ext_vector_type(4))) short vbf4;
typedef __attribute__((ext_vector_type(4))) float vf4;

__device__ __forceinline__ short f2bf(float f) {
  union { float f; unsigned int u; } v; v.f = f;
  unsigned int r = v.u + 0x7fffu + ((v.u >> 16) & 1u);
  return (short)(r >> 16);
}

__device__ __forceinline__ void gload16(const void* g, void* l) {
  __builtin_amdgcn_global_load_lds(
      (const __attribute__((address_space(1))) unsigned int*)g,
      (__attribute__((address_space(3))) unsigned int*)l, 16, 0, 0);
}

// ---------- f32 -> bf16 convert, 4 elems/thread, exact grids ----------
__global__ __launch_bounds__(256) void cvt_kernel(const float* __restrict__ src,
                                                  short* __restrict__ dst, int n) {
  int i = (blockIdx.x * 256 + threadIdx.x) * 4;
  if (i >= n) return;
  float4 v = *(const float4*)(src + i);
  vbf4 o;
  o.x = f2bf(v.x); o.y = f2bf(v.y); o.z = f2bf(v.z); o.w = f2bf(v.w);
  *(vbf4*)(dst + i) = o;
}

// ---------- GEMM C = A * B^T  (A [M][K], B [N][K], both bf16, K-contiguous) ----------
// EPI 0: QKV projection epilogue (scatter to Q/K/Vt head layouts, Q pre-scaled 0.125)
// EPI 1: output projection epilogue (add bias, f32 out [M][1024])
template <int EPI>
__global__ __launch_bounds__(256) void gemm_bt(
    const short* __restrict__ A, const short* __restrict__ Bw, int K,
    short* __restrict__ qb, short* __restrict__ kb, short* __restrict__ vtb,
    const float* __restrict__ bo, float* __restrict__ outp) {
  __shared__ __align__(16) short As[128 * 32];
  __shared__ __align__(16) short Bs[128 * 32];
  const int lane = threadIdx.x & 63;
  const int w = threadIdx.x >> 6;
  const int wr = w >> 1, wc = w & 1;
  const int m0 = blockIdx.y * 128, n0 = blockIdx.x * 128;

  const short* ga = A + (size_t)(m0 + w * 32 + (lane >> 2)) * K + (lane & 3) * 8;
  const short* gb = Bw + (size_t)(n0 + w * 32 + (lane >> 2)) * K + (lane & 3) * 8;
  short* lA = As + w * 1024;
  short* lB = Bs + w * 1024;

  vf4 acc[4][4];
#pragma unroll
  for (int i = 0; i < 4; ++i)
#pragma unroll
    for (int j = 0; j < 4; ++j) acc[i][j] = (vf4){0.f, 0.f, 0.f, 0.f};

  const int ar = wr * 64 + (lane & 15);
  const int br = wc * 64 + (lane & 15);
  const int kk = (lane >> 4) * 8;

  for (int k0 = 0; k0 < K; k0 += 32) {
    gload16(ga + k0, lA);
    gload16(ga + k0 + 16 * K, lA + 512);
    gload16(gb + k0, lB);
    gload16(gb + k0 + 16 * K, lB + 512);
    __syncthreads();
    vbf8 af[4], bfr[4];
#pragma unroll
    for (int mf = 0; mf < 4; ++mf) af[mf] = *(const vbf8*)(As + (ar + mf * 16) * 32 + kk);
#pragma unroll
    for (int nf = 0; nf < 4; ++nf) bfr[nf] = *(const vbf8*)(Bs + (br + nf * 16) * 32 + kk);
#pragma unroll
    for (int mf = 0; mf < 4; ++mf)
#pragma unroll
      for (int nf = 0; nf < 4; ++nf)
        acc[mf][nf] = __builtin_amdgcn_mfma_f32_16x16x32_bf16(af[mf], bfr[nf], acc[mf][nf], 0, 0, 0);
    __syncthreads();
  }

#pragma unroll
  for (int mf = 0; mf < 4; ++mf) {
    const int mbase = m0 + wr * 64 + mf * 16 + (lane >> 4) * 4;
#pragma unroll
    for (int nf = 0; nf < 4; ++nf) {
      vf4 v = acc[mf][nf];
      const int n = n0 + wc * 64 + nf * 16 + (lane & 15);
      if (EPI == 0) {
        const int region = n >> 10;  // 0=Q 1=K 2=V
        const int nn = n & 1023;
        const int h = nn >> 6, d = nn & 63;
        if (region == 0) {
#pragma unroll
          for (int i = 0; i < 4; ++i) {
            const int m = mbase + i;
            const int b = m >> 11, t = m & 2047;
            qb[((size_t)(b * 16 + h) * 2048 + t) * 64 + d] = f2bf(v[i] * 0.125f);
          }
        } else if (region == 1) {
#pragma unroll
          for (int i = 0; i < 4; ++i) {
            const int m = mbase + i;
            const int b = m >> 11, t = m & 2047;
            kb[((size_t)(b * 16 + h) * 2048 + t) * 64 + d] = f2bf(v[i]);
          }
        } else {
          const int b = mbase >> 11, t = mbase & 2047;
          vbf4 o;
          o.x = f2bf(v.x); o.y = f2bf(v.y); o.z = f2bf(v.z); o.w = f2bf(v.w);
          *(vbf4*)(vtb + ((size_t)(b * 16 + h) * 64 + d) * 2048 + t) = o;
        }
      } else {
        const float bias = bo[n];
#pragma unroll
        for (int i = 0; i < 4; ++i) {
          const int m = mbase + i;
          outp[(size_t)m * 1024 + n] = v[i] + bias;
        }
      }
    }
  }
}

// ---------- flash attention, causal, barrier-free ----------
// grid (64, H, B), 64 threads = 1 wave owning 32 q-rows. Heavy-first order.
// K/V fragments read directly from global (L2-served; no staging, no barriers).
// Q pre-scaled by 1/sqrt(64). Q/K layout [B,H,T,64]; V transposed [B,H,64,T].
__global__ __launch_bounds__(64) void attn_kernel(
    const short* __restrict__ Qh, const short* __restrict__ Kh,
    const short* __restrict__ Vt, short* __restrict__ ctx) {
  __shared__ __align__(16) short Ps[32 * 68];  // wave-private P round-trip, pad 68

  const int lane = threadIdx.x;
  const int W = (int)gridDim.x - 1 - (int)blockIdx.x;  // heavy blocks first
  const int h = blockIdx.y, b = blockIdx.z;
  const size_t bhoff = (size_t)(b * 16 + h) * 131072;  // 2048*64
  const short* Qp = Qh + bhoff;
  const short* Kp = Kh + bhoff;
  const short* Vp = Vt + bhoff;
  const int wq0 = W * 32;

  // Q fragments in registers for the whole kv loop
  vbf8 qfr[2][2];
#pragma unroll
  for (int qfi = 0; qfi < 2; ++qfi)
#pragma unroll
    for (int ks = 0; ks < 2; ++ks)
      qfr[qfi][ks] = *(const vbf8*)(Qp + (size_t)(wq0 + qfi * 16 + (lane & 15)) * 64 +
                                    ks * 32 + (lane >> 4) * 8);

  vf4 o[2][4];
  float mrow[2][4], lrow[2][4];
#pragma unroll
  for (int qfi = 0; qfi < 2; ++qfi) {
#pragma unroll
    for (int df = 0; df < 4; ++df) o[qfi][df] = (vf4){0.f, 0.f, 0.f, 0.f};
#pragma unroll
    for (int i = 0; i < 4; ++i) { mrow[qfi][i] = -1e30f; lrow[qfi][i] = 0.f; }
  }

  const int nt = (wq0 >> 6) + 1;
  for (int t = 0; t < nt; ++t) {
    const int k0 = t * 64;

    // K fragments: shared by both qfi blocks; 8 x 16B/lane direct global loads
    vbf8 kf8[4][2];
#pragma unroll
    for (int kf = 0; kf < 4; ++kf)
#pragma unroll
      for (int ks = 0; ks < 2; ++ks)
        kf8[kf][ks] = *(const vbf8*)(Kp + (size_t)(k0 + kf * 16 + (lane & 15)) * 64 +
                                     ks * 32 + (lane >> 4) * 8);

    // S = Q K^T for both 16-row q blocks (scale already folded into Q)
    vf4 s[2][4];
#pragma unroll
    for (int qfi = 0; qfi < 2; ++qfi)
#pragma unroll
      for (int kf = 0; kf < 4; ++kf) {
        s[qfi][kf] = (vf4){0.f, 0.f, 0.f, 0.f};
#pragma unroll
        for (int ks = 0; ks < 2; ++ks)
          s[qfi][kf] = __builtin_amdgcn_mfma_f32_16x16x32_bf16(qfr[qfi][ks], kf8[kf][ks],
                                                               s[qfi][kf], 0, 0, 0);
      }

    // issue V loads now; they complete under the softmax VALU work
    vbf8 vb[2][4];
#pragma unroll
    for (int ks2 = 0; ks2 < 2; ++ks2)
#pragma unroll
      for (int df = 0; df < 4; ++df)
        vb[ks2][df] = *(const vbf8*)(Vp + (size_t)(df * 16 + (lane & 15)) * 2048 +
                                     k0 + ks2 * 32 + (lane >> 4) * 8);

    const bool needmask = (k0 + 64 > wq0);
#pragma unroll
    for (int qfi = 0; qfi < 2; ++qfi) {
      if (needmask) {
        const int qr = wq0 + qfi * 16 + (lane >> 4) * 4;
#pragma unroll
        for (int kf = 0; kf < 4; ++kf) {
          const int kc = k0 + kf * 16 + (lane & 15);
#pragma unroll
          for (int i = 0; i < 4; ++i)
            if (kc > qr + i) s[qfi][kf][i] = -1e30f;
        }
      }
      // online softmax: rows parallel across the four 16-lane groups
      float tmax[4], al[4], rs[4];
#pragma unroll
      for (int i = 0; i < 4; ++i) {
        float mx = fmaxf(fmaxf(s[qfi][0][i], s[qfi][1][i]), fmaxf(s[qfi][2][i], s[qfi][3][i]));
        mx = fmaxf(mx, __shfl_xor(mx, 1));
        mx = fmaxf(mx, __shfl_xor(mx, 2));
        mx = fmaxf(mx, __shfl_xor(mx, 4));
        mx = fmaxf(mx, __shfl_xor(mx, 8));
        tmax[i] = mx;
      }
#pragma unroll
      for (int i = 0; i < 4; ++i) {
        const float mn = fmaxf(mrow[qfi][i], tmax[i]);
        al[i] = __expf(mrow[qfi][i] - mn);
        mrow[qfi][i] = mn;
        rs[i] = 0.f;
      }
#pragma unroll
      for (int kf = 0; kf < 4; ++kf)
#pragma unroll
        for (int i = 0; i < 4; ++i) {
          const float p = __expf(s[qfi][kf][i] - mrow[qfi][i]);
          s[qfi][kf][i] = p;
          rs[i] += p;
        }
#pragma unroll
      for (int i = 0; i < 4; ++i) {
        rs[i] += __shfl_xor(rs[i], 1);
        rs[i] += __shfl_xor(rs[i], 2);
        rs[i] += __shfl_xor(rs[i], 4);
        rs[i] += __shfl_xor(rs[i], 8);
        lrow[qfi][i] = lrow[qfi][i] * al[i] + rs[i];
      }
#pragma unroll
      for (int df = 0; df < 4; ++df)
#pragma unroll
        for (int i = 0; i < 4; ++i) o[qfi][df][i] *= al[i];

      // P (C-layout) -> LDS -> A-layout
      const int prow = (lane >> 4) * 4;
#pragma unroll
      for (int kf = 0; kf < 4; ++kf)
#pragma unroll
        for (int i = 0; i < 4; ++i)
          Ps[(qfi * 16 + prow + i) * 68 + kf * 16 + (lane & 15)] = f2bf(s[qfi][kf][i]);
    }

    // ctx += P @ V
#pragma unroll
    for (int qfi = 0; qfi < 2; ++qfi) {
#pragma unroll
      for (int ks2 = 0; ks2 < 2; ++ks2) {
        const vbf8 pa = *(const vbf8*)(Ps + (qfi * 16 + (lane & 15)) * 68 +
                                       ks2 * 32 + (lane >> 4) * 8);
#pragma unroll
        for (int df = 0; df < 4; ++df)
          o[qfi][df] = __builtin_amdgcn_mfma_f32_16x16x32_bf16(pa, vb[ks2][df],
                                                               o[qfi][df], 0, 0, 0);
      }
    }
  }

  // normalize + write ctx [B*T][1024] bf16
#pragma unroll
  for (int qfi = 0; qfi < 2; ++qfi) {
#pragma unroll
    for (int i = 0; i < 4; ++i) {
      const float inv = 1.f / lrow[qfi][i];
      const int q = wq0 + qfi * 16 + (lane >> 4) * 4 + i;
      short* dst = ctx + (size_t)(b * 2048 + q) * 1024 + h * 64;
#pragma unroll
      for (int df = 0; df < 4; ++df)
        dst[df * 16 + (lane & 15)] = f2bf(o[qfi][df][i] * inv);
    }
  }
}

extern "C" void kernel_launch(void* const* d_in, const int* in_sizes, int n_in,
                              void* d_out, int out_size, void* d_ws, size_t ws_size,
                              hipStream_t stream) {
  const float* x  = (const float*)d_in[0];
  const float* Wq = (const float*)d_in[1];
  const float* Wk = (const float*)d_in[2];
  const float* Wv = (const float*)d_in[3];
  const float* Wo = (const float*)d_in[4];
  const float* bo = (const float*)d_in[5];
  float* out = (float*)d_out;

  char* ws = (char*)d_ws;
  short* xb   = (short*)(ws);                  // 16 MB (x bf16), reused as ctx later
  short* wqkv = (short*)(ws + 16777216);       // 6 MB, reused as Wo bf16 later
  short* qb   = (short*)(ws + 23068672);       // 16 MB
  short* kb   = (short*)(ws + 39845888);       // 16 MB
  short* vtb  = (short*)(ws + 56623104);       // 16 MB  (V transposed [B,H,64,T])
  short* ctxb = xb;
  short* wob  = wqkv;

  cvt_kernel<<<8192, 256, 0, stream>>>(x, xb, 8388608);
  cvt_kernel<<<1024, 256, 0, stream>>>(Wq, wqkv, 1048576);
  cvt_kernel<<<1024, 256, 0, stream>>>(Wk, wqkv + 1048576, 1048576);
  cvt_kernel<<<1024, 256, 0, stream>>>(Wv, wqkv + 2097152, 1048576);
  gemm_bt<0><<<dim3(24, 64), 256, 0, stream>>>(xb, wqkv, 1024, qb, kb, vtb, nullptr, nullptr);
  cvt_kernel<<<1024, 256, 0, stream>>>(Wo, wob, 1048576);
  attn_kernel<<<dim3(64, 16, 4), 64, 0, stream>>>(qb, kb, vtb, ctxb);
  gemm_bt<1><<<dim3(8, 64), 256, 0, stream>>>(ctxb, wob, 1024, nullptr, nullptr, nullptr, bo, out);
}

// Round 3
// 281.280 us; speedup vs baseline: 1.2582x; 1.1990x over previous
//
#include <hip/hip_runtime.h>

typedef __attribute__((ext_vector_type(8))) short vbf8;
typedef __attribute__((ext_vector_type(4))) short vbf4;
typedef __attribute__((ext_vector_type(4))) float vf4;

__device__ __forceinline__ short f2bf(float f) {
  union { float f; unsigned int u; } v; v.f = f;
  unsigned int r = v.u + 0x7fffu + ((v.u >> 16) & 1u);
  return (short)(r >> 16);
}

__device__ __forceinline__ void gload16(const void* g, void* l) {
  __builtin_amdgcn_global_load_lds(
      (const __attribute__((address_space(1))) unsigned int*)g,
      (__attribute__((address_space(3))) unsigned int*)l, 16, 0, 0);
}

// ---------- f32 -> bf16 convert, 4 elems/thread, exact grids ----------
__global__ __launch_bounds__(256) void cvt_kernel(const float* __restrict__ src,
                                                  short* __restrict__ dst, int n) {
  int i = (blockIdx.x * 256 + threadIdx.x) * 4;
  if (i >= n) return;
  float4 v = *(const float4*)(src + i);
  vbf4 o;
  o.x = f2bf(v.x); o.y = f2bf(v.y); o.z = f2bf(v.z); o.w = f2bf(v.w);
  *(vbf4*)(dst + i) = o;
}

// ---------- GEMM C = A * B^T  (A [M][K], B [N][K], both bf16, K-contiguous) ----------
template <int EPI>
__global__ __launch_bounds__(256) void gemm_bt(
    const short* __restrict__ A, const short* __restrict__ Bw, int K,
    short* __restrict__ qb, short* __restrict__ kb, short* __restrict__ vtb,
    const float* __restrict__ bo, float* __restrict__ outp) {
  __shared__ __align__(16) short As[128 * 32];
  __shared__ __align__(16) short Bs[128 * 32];
  const int lane = threadIdx.x & 63;
  const int w = threadIdx.x >> 6;
  const int wr = w >> 1, wc = w & 1;
  const int m0 = blockIdx.y * 128, n0 = blockIdx.x * 128;

  const short* ga = A + (size_t)(m0 + w * 32 + (lane >> 2)) * K + (lane & 3) * 8;
  const short* gb = Bw + (size_t)(n0 + w * 32 + (lane >> 2)) * K + (lane & 3) * 8;
  short* lA = As + w * 1024;
  short* lB = Bs + w * 1024;

  vf4 acc[4][4];
#pragma unroll
  for (int i = 0; i < 4; ++i)
#pragma unroll
    for (int j = 0; j < 4; ++j) acc[i][j] = (vf4){0.f, 0.f, 0.f, 0.f};

  const int ar = wr * 64 + (lane & 15);
  const int br = wc * 64 + (lane & 15);
  const int kk = (lane >> 4) * 8;

  for (int k0 = 0; k0 < K; k0 += 32) {
    gload16(ga + k0, lA);
    gload16(ga + k0 + 16 * K, lA + 512);
    gload16(gb + k0, lB);
    gload16(gb + k0 + 16 * K, lB + 512);
    __syncthreads();
    vbf8 af[4], bfr[4];
#pragma unroll
    for (int mf = 0; mf < 4; ++mf) af[mf] = *(const vbf8*)(As + (ar + mf * 16) * 32 + kk);
#pragma unroll
    for (int nf = 0; nf < 4; ++nf) bfr[nf] = *(const vbf8*)(Bs + (br + nf * 16) * 32 + kk);
#pragma unroll
    for (int mf = 0; mf < 4; ++mf)
#pragma unroll
      for (int nf = 0; nf < 4; ++nf)
        acc[mf][nf] = __builtin_amdgcn_mfma_f32_16x16x32_bf16(af[mf], bfr[nf], acc[mf][nf], 0, 0, 0);
    __syncthreads();
  }

#pragma unroll
  for (int mf = 0; mf < 4; ++mf) {
    const int mbase = m0 + wr * 64 + mf * 16 + (lane >> 4) * 4;
#pragma unroll
    for (int nf = 0; nf < 4; ++nf) {
      vf4 v = acc[mf][nf];
      const int n = n0 + wc * 64 + nf * 16 + (lane & 15);
      if (EPI == 0) {
        const int region = n >> 10;  // 0=Q 1=K 2=V
        const int nn = n & 1023;
        const int h = nn >> 6, d = nn & 63;
        if (region == 0) {
#pragma unroll
          for (int i = 0; i < 4; ++i) {
            const int m = mbase + i;
            const int b = m >> 11, t = m & 2047;
            qb[((size_t)(b * 16 + h) * 2048 + t) * 64 + d] = f2bf(v[i] * 0.125f);
          }
        } else if (region == 1) {
#pragma unroll
          for (int i = 0; i < 4; ++i) {
            const int m = mbase + i;
            const int b = m >> 11, t = m & 2047;
            kb[((size_t)(b * 16 + h) * 2048 + t) * 64 + d] = f2bf(v[i]);
          }
        } else {
          const int b = mbase >> 11, t = mbase & 2047;
          vbf4 o;
          o.x = f2bf(v.x); o.y = f2bf(v.y); o.z = f2bf(v.z); o.w = f2bf(v.w);
          *(vbf4*)(vtb + ((size_t)(b * 16 + h) * 64 + d) * 2048 + t) = o;
        }
      } else {
        const float bias = bo[n];
#pragma unroll
        for (int i = 0; i < 4; ++i) {
          const int m = mbase + i;
          outp[(size_t)m * 1024 + n] = v[i] + bias;
        }
      }
    }
  }
}

// ---------- flash attention, causal, barrier-free, XCD-affine ----------
// 4096 single-wave blocks. bid -> (xcd, pair, W) so that XCD x (= bid%8) only
// touches (b,h) pairs {x, x+8,...}: 8 pairs x 512KB K/V = 4MB -> L2-resident.
// Heavy W first within each XCD. K double-buffered in registers (prefetch t+1).
__global__ __launch_bounds__(64) void attn_kernel(
    const short* __restrict__ Qh, const short* __restrict__ Kh,
    const short* __restrict__ Vt, short* __restrict__ ctx) {
  __shared__ __align__(16) short Ps[32 * 68];

  const int lane = threadIdx.x;
  const int bid = blockIdx.x;
  const int x = bid & 7;
  const int kidx = bid >> 3;
  const int p_idx = kidx & 7;
  const int W = 63 - (kidx >> 3);
  const int pair = x + 8 * p_idx;      // (b*16+h) in 0..63
  const int b = pair >> 4, h = pair & 15;

  const size_t bhoff = (size_t)pair * 131072;  // 2048*64
  const short* Qp = Qh + bhoff;
  const short* Kp = Kh + bhoff;
  const short* Vp = Vt + bhoff;
  const int wq0 = W * 32;

  vbf8 qfr[2][2];
#pragma unroll
  for (int qfi = 0; qfi < 2; ++qfi)
#pragma unroll
    for (int ks = 0; ks < 2; ++ks)
      qfr[qfi][ks] = *(const vbf8*)(Qp + (size_t)(wq0 + qfi * 16 + (lane & 15)) * 64 +
                                    ks * 32 + (lane >> 4) * 8);

  vf4 o[2][4];
  float mrow[2][4], lrow[2][4];
#pragma unroll
  for (int qfi = 0; qfi < 2; ++qfi) {
#pragma unroll
    for (int df = 0; df < 4; ++df) o[qfi][df] = (vf4){0.f, 0.f, 0.f, 0.f};
#pragma unroll
    for (int i = 0; i < 4; ++i) { mrow[qfi][i] = -1e30f; lrow[qfi][i] = 0.f; }
  }

  const int nt = (wq0 >> 6) + 1;

  vbf8 kA[4][2], kB[4][2];
  // prologue: K(0) -> kA
#pragma unroll
  for (int kf = 0; kf < 4; ++kf)
#pragma unroll
    for (int ks = 0; ks < 2; ++ks)
      kA[kf][ks] = *(const vbf8*)(Kp + (size_t)(kf * 16 + (lane & 15)) * 64 +
                                  ks * 32 + (lane >> 4) * 8);

  auto tile = [&](int t, vbf8 (&kc)[4][2], vbf8 (&kn)[4][2]) {
    const int k0 = t * 64;

    // V(t) loads — fly under QK+softmax
    vbf8 vb[2][4];
#pragma unroll
    for (int ks2 = 0; ks2 < 2; ++ks2)
#pragma unroll
      for (int df = 0; df < 4; ++df)
        vb[ks2][df] = *(const vbf8*)(Vp + (size_t)(df * 16 + (lane & 15)) * 2048 +
                                     k0 + ks2 * 32 + (lane >> 4) * 8);
    // prefetch K(t+1) — lands during softmax+PV
    if (t + 1 < nt) {
      const int kn0 = k0 + 64;
#pragma unroll
      for (int kf = 0; kf < 4; ++kf)
#pragma unroll
        for (int ks = 0; ks < 2; ++ks)
          kn[kf][ks] = *(const vbf8*)(Kp + (size_t)(kn0 + kf * 16 + (lane & 15)) * 64 +
                                      ks * 32 + (lane >> 4) * 8);
    }

    vf4 s[2][4];
    __builtin_amdgcn_s_setprio(1);
#pragma unroll
    for (int qfi = 0; qfi < 2; ++qfi)
#pragma unroll
      for (int kf = 0; kf < 4; ++kf) {
        s[qfi][kf] = (vf4){0.f, 0.f, 0.f, 0.f};
#pragma unroll
        for (int ks = 0; ks < 2; ++ks)
          s[qfi][kf] = __builtin_amdgcn_mfma_f32_16x16x32_bf16(qfr[qfi][ks], kc[kf][ks],
                                                               s[qfi][kf], 0, 0, 0);
      }
    __builtin_amdgcn_s_setprio(0);

    const bool needmask = (k0 + 64 > wq0);
#pragma unroll
    for (int qfi = 0; qfi < 2; ++qfi) {
      if (needmask) {
        const int qr = wq0 + qfi * 16 + (lane >> 4) * 4;
#pragma unroll
        for (int kf = 0; kf < 4; ++kf) {
          const int kc2 = k0 + kf * 16 + (lane & 15);
#pragma unroll
          for (int i = 0; i < 4; ++i)
            if (kc2 > qr + i) s[qfi][kf][i] = -1e30f;
        }
      }
      float tmax[4], al[4], rs[4];
#pragma unroll
      for (int i = 0; i < 4; ++i) {
        float mx = fmaxf(fmaxf(s[qfi][0][i], s[qfi][1][i]), fmaxf(s[qfi][2][i], s[qfi][3][i]));
        mx = fmaxf(mx, __shfl_xor(mx, 1));
        mx = fmaxf(mx, __shfl_xor(mx, 2));
        mx = fmaxf(mx, __shfl_xor(mx, 4));
        mx = fmaxf(mx, __shfl_xor(mx, 8));
        tmax[i] = mx;
      }
#pragma unroll
      for (int i = 0; i < 4; ++i) {
        const float mn = fmaxf(mrow[qfi][i], tmax[i]);
        al[i] = __expf(mrow[qfi][i] - mn);
        mrow[qfi][i] = mn;
        rs[i] = 0.f;
      }
#pragma unroll
      for (int kf = 0; kf < 4; ++kf)
#pragma unroll
        for (int i = 0; i < 4; ++i) {
          const float p = __expf(s[qfi][kf][i] - mrow[qfi][i]);
          s[qfi][kf][i] = p;
          rs[i] += p;
        }
#pragma unroll
      for (int i = 0; i < 4; ++i) {
        rs[i] += __shfl_xor(rs[i], 1);
        rs[i] += __shfl_xor(rs[i], 2);
        rs[i] += __shfl_xor(rs[i], 4);
        rs[i] += __shfl_xor(rs[i], 8);
        lrow[qfi][i] = lrow[qfi][i] * al[i] + rs[i];
      }
#pragma unroll
      for (int df = 0; df < 4; ++df)
#pragma unroll
        for (int i = 0; i < 4; ++i) o[qfi][df][i] *= al[i];

      const int prow = (lane >> 4) * 4;
#pragma unroll
      for (int kf = 0; kf < 4; ++kf)
#pragma unroll
        for (int i = 0; i < 4; ++i)
          Ps[(qfi * 16 + prow + i) * 68 + kf * 16 + (lane & 15)] = f2bf(s[qfi][kf][i]);
    }

    __builtin_amdgcn_s_setprio(1);
#pragma unroll
    for (int qfi = 0; qfi < 2; ++qfi) {
#pragma unroll
      for (int ks2 = 0; ks2 < 2; ++ks2) {
        const vbf8 pa = *(const vbf8*)(Ps + (qfi * 16 + (lane & 15)) * 68 +
                                       ks2 * 32 + (lane >> 4) * 8);
#pragma unroll
        for (int df = 0; df < 4; ++df)
          o[qfi][df] = __builtin_amdgcn_mfma_f32_16x16x32_bf16(pa, vb[ks2][df],
                                                               o[qfi][df], 0, 0, 0);
      }
    }
    __builtin_amdgcn_s_setprio(0);
  };

  for (int t = 0; t < nt; t += 2) {
    tile(t, kA, kB);
    if (t + 1 < nt) tile(t + 1, kB, kA);
  }

#pragma unroll
  for (int qfi = 0; qfi < 2; ++qfi) {
#pragma unroll
    for (int i = 0; i < 4; ++i) {
      const float inv = 1.f / lrow[qfi][i];
      const int q = wq0 + qfi * 16 + (lane >> 4) * 4 + i;
      short* dst = ctx + (size_t)(b * 2048 + q) * 1024 + h * 64;
#pragma unroll
      for (int df = 0; df < 4; ++df)
        dst[df * 16 + (lane & 15)] = f2bf(o[qfi][df][i] * inv);
    }
  }
}

extern "C" void kernel_launch(void* const* d_in, const int* in_sizes, int n_in,
                              void* d_out, int out_size, void* d_ws, size_t ws_size,
                              hipStream_t stream) {
  const float* x  = (const float*)d_in[0];
  const float* Wq = (const float*)d_in[1];
  const float* Wk = (const float*)d_in[2];
  const float* Wv = (const float*)d_in[3];
  const float* Wo = (const float*)d_in[4];
  const float* bo = (const float*)d_in[5];
  float* out = (float*)d_out;

  char* ws = (char*)d_ws;
  short* xb   = (short*)(ws);                  // 16 MB (x bf16), reused as ctx later
  short* wqkv = (short*)(ws + 16777216);       // 6 MB, reused as Wo bf16 later
  short* qb   = (short*)(ws + 23068672);       // 16 MB
  short* kb   = (short*)(ws + 39845888);       // 16 MB
  short* vtb  = (short*)(ws + 56623104);       // 16 MB  (V transposed [B,H,64,T])
  short* ctxb = xb;
  short* wob  = wqkv;

  cvt_kernel<<<8192, 256, 0, stream>>>(x, xb, 8388608);
  cvt_kernel<<<1024, 256, 0, stream>>>(Wq, wqkv, 1048576);
  cvt_kernel<<<1024, 256, 0, stream>>>(Wk, wqkv + 1048576, 1048576);
  cvt_kernel<<<1024, 256, 0, stream>>>(Wv, wqkv + 2097152, 1048576);
  gemm_bt<0><<<dim3(24, 64), 256, 0, stream>>>(xb, wqkv, 1024, qb, kb, vtb, nullptr, nullptr);
  cvt_kernel<<<1024, 256, 0, stream>>>(Wo, wob, 1048576);
  attn_kernel<<<4096, 64, 0, stream>>>(qb, kb, vtb, ctxb);
  gemm_bt<1><<<dim3(8, 64), 256, 0, stream>>>(ctxb, wob, 1024, nullptr, nullptr, nullptr, bo, out);
}